// Round 1
// baseline (251.110 us; speedup 1.0000x reference)
//
#include <hip/hip_runtime.h>
#include <hip/hip_bf16.h>

// Problem constants (from reference)
#define B 16
#define C 128
#define H 192
#define W 192
#define HID 32
#define K 2
#define PLANE (H*W)           // 36864
#define NPLANES (B*C)         // 2048

// ---------------- Kernel 1: global average pool per (b,c) plane ----------------
__global__ __launch_bounds__(256) void pool_kernel(const float* __restrict__ x,
                                                   float* __restrict__ pooled) {
    const int plane = blockIdx.x;  // b*C + c
    const float4* px4 = (const float4*)(x + (size_t)plane * PLANE);  // 9216 float4
    float s = 0.f;
    for (int i = threadIdx.x; i < PLANE / 4; i += 256) {
        float4 v = px4[i];
        s += v.x + v.y + v.z + v.w;
    }
    // wave64 reduce
    for (int off = 32; off; off >>= 1) s += __shfl_down(s, off, 64);
    __shared__ float wsum[4];
    const int lane = threadIdx.x & 63, wid = threadIdx.x >> 6;
    if (lane == 0) wsum[wid] = s;
    __syncthreads();
    if (threadIdx.x == 0) {
        pooled[plane] = (wsum[0] + wsum[1] + wsum[2] + wsum[3]) * (1.0f / (float)PLANE);
    }
}

// ---------------- Kernel 2: selector MLP + softmax + weight combine ----------------
__global__ __launch_bounds__(512) void selector_kernel(const float* __restrict__ pooled,
                                                       const float* __restrict__ w1,
                                                       const float* __restrict__ b1,
                                                       const float* __restrict__ w2,
                                                       const float* __restrict__ b2,
                                                       const float* __restrict__ wb,
                                                       float* __restrict__ cw) {
    __shared__ float h[B][HID];
    __shared__ float attn[B][K];
    const int tid = threadIdx.x;

    // h[b][j] = relu(sum_c pooled[b,c] * w1[j,c] + b1[j])   (512 = 16*32 threads)
    {
        const int b = tid >> 5, j = tid & 31;
        float s = b1[j];
        const float* pb = pooled + b * C;
        const float* wj = w1 + j * C;
        #pragma unroll 8
        for (int c = 0; c < C; ++c) s += pb[c] * wj[c];
        h[b][j] = fmaxf(s, 0.f);
    }
    __syncthreads();
    // logits[b][k]
    if (tid < B * K) {
        const int b = tid >> 1, k = tid & 1;
        float s = b2[k];
        const float* wk = w2 + k * HID;
        #pragma unroll
        for (int j = 0; j < HID; ++j) s += h[b][j] * wk[j];
        attn[b][k] = s;
    }
    __syncthreads();
    // softmax over K=2
    if (tid < B) {
        const float a0 = attn[tid][0], a1 = attn[tid][1];
        const float m = fmaxf(a0, a1);
        const float e0 = __expf(a0 - m), e1 = __expf(a1 - m);
        const float inv = 1.f / (e0 + e1);
        attn[tid][0] = e0 * inv;
        attn[tid][1] = e1 * inv;
    }
    __syncthreads();
    // cw[b][c][9] = attn[b][0]*wb[0][c][9] + attn[b][1]*wb[1][c][9]
    for (int i = tid; i < B * C * 9; i += 512) {
        const int b = i / (C * 9);
        const int ci = i % (C * 9);
        cw[i] = attn[b][0] * wb[ci] + attn[b][1] * wb[C * 9 + ci];
    }
}

// ---------------- Kernel 3: depthwise 3x3 conv (pad 1) + bias ----------------
// Each thread produces 4 contiguous outputs (aligned float4 store).
// Per plane: 192*192/4 = 9216 strips -> 36 blocks of 256 threads.
__global__ __launch_bounds__(256) void conv_kernel(const float* __restrict__ x,
                                                   const float* __restrict__ cw,
                                                   const float* __restrict__ bias,
                                                   float* __restrict__ out) {
    const int bid = blockIdx.x;
    const int plane = bid / 36;          // b*C + c  (uniform per block)
    const int chunk = bid % 36;
    const int c = plane & (C - 1);

    const float* w = cw + plane * 9;
    const float w00 = w[0], w01 = w[1], w02 = w[2];
    const float w10 = w[3], w11 = w[4], w12 = w[5];
    const float w20 = w[6], w21 = w[7], w22 = w[8];
    const float bv = bias[c];

    const int strip = chunk * 256 + threadIdx.x;   // 0..9215
    const int y  = strip / (W / 4);
    const int x0 = (strip % (W / 4)) * 4;

    const float* px = x + (size_t)plane * PLANE;

    float a0 = bv, a1 = bv, a2 = bv, a3 = bv;

    #pragma unroll
    for (int dy = -1; dy <= 1; ++dy) {
        const int r = y + dy;
        if (r < 0 || r >= H) continue;
        const float wl = (dy == -1) ? w00 : ((dy == 0) ? w10 : w20);
        const float wc = (dy == -1) ? w01 : ((dy == 0) ? w11 : w21);
        const float wr = (dy == -1) ? w02 : ((dy == 0) ? w12 : w22);
        const float* row = px + r * W;
        const float4 cur = *(const float4*)(row + x0);
        const float left  = (x0 > 0)     ? row[x0 - 1] : 0.f;
        const float right = (x0 + 4 < W) ? row[x0 + 4] : 0.f;
        a0 = fmaf(wl, left,  fmaf(wc, cur.x, fmaf(wr, cur.y, a0)));
        a1 = fmaf(wl, cur.x, fmaf(wc, cur.y, fmaf(wr, cur.z, a1)));
        a2 = fmaf(wl, cur.y, fmaf(wc, cur.z, fmaf(wr, cur.w, a2)));
        a3 = fmaf(wl, cur.z, fmaf(wc, cur.w, fmaf(wr, right, a3)));
    }

    float4 o = make_float4(a0, a1, a2, a3);
    *(float4*)(out + (size_t)plane * PLANE + y * W + x0) = o;
}

extern "C" void kernel_launch(void* const* d_in, const int* in_sizes, int n_in,
                              void* d_out, int out_size, void* d_ws, size_t ws_size,
                              hipStream_t stream) {
    const float* x    = (const float*)d_in[0];
    const float* w1   = (const float*)d_in[1];
    const float* b1   = (const float*)d_in[2];
    const float* w2   = (const float*)d_in[3];
    const float* b2   = (const float*)d_in[4];
    const float* wb   = (const float*)d_in[5];
    const float* bias = (const float*)d_in[6];
    float* out = (float*)d_out;

    // workspace layout: pooled [2048] floats, cw [2048*9] floats
    float* pooled = (float*)d_ws;
    float* cw     = pooled + NPLANES;

    pool_kernel<<<NPLANES, 256, 0, stream>>>(x, pooled);
    selector_kernel<<<1, 512, 0, stream>>>(pooled, w1, b1, w2, b2, wb, cw);
    conv_kernel<<<NPLANES * 36, 256, 0, stream>>>(x, cw, bias, out);
}

// Round 3
// 204.484 us; speedup vs baseline: 1.2280x; 1.2280x over previous
//
#include <hip/hip_runtime.h>
#include <hip/hip_bf16.h>

// Problem constants (from reference)
#define B 16
#define C 128
#define H 192
#define W 192
#define HID 32
#define K 2
#define PLANE (H*W)           // 36864
#define NPLANES (B*C)         // 2048
#define RB 8                  // output rows per thread (vertical register blocking)

typedef float floatx4 __attribute__((ext_vector_type(4)));

// ---------------- Kernel 1: global average pool per (b,c) plane ----------------
__global__ __launch_bounds__(256) void pool_kernel(const float* __restrict__ x,
                                                   float* __restrict__ pooled) {
    const int plane = blockIdx.x;  // b*C + c
    const float4* px4 = (const float4*)(x + (size_t)plane * PLANE);  // 9216 float4
    float s = 0.f;
    for (int i = threadIdx.x; i < PLANE / 4; i += 256) {
        float4 v = px4[i];
        s += v.x + v.y + v.z + v.w;
    }
    // wave64 reduce
    for (int off = 32; off; off >>= 1) s += __shfl_down(s, off, 64);
    __shared__ float wsum[4];
    const int lane = threadIdx.x & 63, wid = threadIdx.x >> 6;
    if (lane == 0) wsum[wid] = s;
    __syncthreads();
    if (threadIdx.x == 0) {
        pooled[plane] = (wsum[0] + wsum[1] + wsum[2] + wsum[3]) * (1.0f / (float)PLANE);
    }
}

// ---------------- Kernel 2: selector MLP + softmax + weight combine ----------------
__global__ __launch_bounds__(512) void selector_kernel(const float* __restrict__ pooled,
                                                       const float* __restrict__ w1,
                                                       const float* __restrict__ b1,
                                                       const float* __restrict__ w2,
                                                       const float* __restrict__ b2,
                                                       const float* __restrict__ wb,
                                                       float* __restrict__ cw) {
    __shared__ float h[B][HID];
    __shared__ float attn[B][K];
    const int tid = threadIdx.x;

    // h[b][j] = relu(sum_c pooled[b,c] * w1[j,c] + b1[j])   (512 = 16*32 threads)
    {
        const int b = tid >> 5, j = tid & 31;
        float s = b1[j];
        const float* pb = pooled + b * C;
        const float* wj = w1 + j * C;
        #pragma unroll 8
        for (int c = 0; c < C; ++c) s += pb[c] * wj[c];
        h[b][j] = fmaxf(s, 0.f);
    }
    __syncthreads();
    // logits[b][k]
    if (tid < B * K) {
        const int b = tid >> 1, k = tid & 1;
        float s = b2[k];
        const float* wk = w2 + k * HID;
        #pragma unroll
        for (int j = 0; j < HID; ++j) s += h[b][j] * wk[j];
        attn[b][k] = s;
    }
    __syncthreads();
    // softmax over K=2
    if (tid < B) {
        const float a0 = attn[tid][0], a1 = attn[tid][1];
        const float m = fmaxf(a0, a1);
        const float e0 = __expf(a0 - m), e1 = __expf(a1 - m);
        const float inv = 1.f / (e0 + e1);
        attn[tid][0] = e0 * inv;
        attn[tid][1] = e1 * inv;
    }
    __syncthreads();
    // cw[b][c][9] = attn[b][0]*wb[0][c][9] + attn[b][1]*wb[1][c][9]
    for (int i = tid; i < B * C * 9; i += 512) {
        const int b = i / (C * 9);
        const int ci = i % (C * 9);
        cw[i] = attn[b][0] * wb[ci] + attn[b][1] * wb[C * 9 + ci];
    }
}

// ---------------- Kernel 3: depthwise 3x3 conv (pad 1) + bias ----------------
// Register-blocked: each thread computes a 4-wide x 8-tall output tile.
// Each input row is loaded ONCE (1 float4 + 2 halo scalars) and feeds 3
// output rows (top/mid/bottom taps) held in registers.
// Block = 576 threads (9 waves) = half a plane (12 bands x 48 col-strips).
// plane = blockIdx.x>>1 is block-uniform -> weights/bias via s_load.
__global__ __launch_bounds__(576) void conv_kernel(const float* __restrict__ x,
                                                   const float* __restrict__ cw,
                                                   const float* __restrict__ bias,
                                                   float* __restrict__ out) {
    const int plane = blockIdx.x >> 1;       // b*C + c (block-uniform)
    const int half  = blockIdx.x & 1;
    const int tid   = threadIdx.x;
    const int xq    = tid % 48;              // col strip (4 floats)
    const int band  = tid / 48 + half * 12;  // 0..23 (8-row band)
    const int c     = plane & (C - 1);

    const float* w = cw + plane * 9;
    const float w00 = w[0], w01 = w[1], w02 = w[2];
    const float w10 = w[3], w11 = w[4], w12 = w[5];
    const float w20 = w[6], w21 = w[7], w22 = w[8];
    const float bv = bias[c];

    const int x0 = xq * 4;
    const int y0 = band * RB;
    const float* px = x + (size_t)plane * PLANE;

    float acc[RB][4];
    #pragma unroll
    for (int j = 0; j < RB; ++j) {
        acc[j][0] = bv; acc[j][1] = bv; acc[j][2] = bv; acc[j][3] = bv;
    }

    #pragma unroll
    for (int i = 0; i < RB + 2; ++i) {
        const int r = y0 - 1 + i;
        float v0, v1, v2, v3, v4, v5;
        if (r >= 0 && r < H) {
            const float* rp = px + r * W + x0;
            const float4 cur = *(const float4*)rp;
            v1 = cur.x; v2 = cur.y; v3 = cur.z; v4 = cur.w;
            v0 = (x0 > 0)     ? rp[-1] : 0.f;
            v5 = (x0 + 4 < W) ? rp[4]  : 0.f;
        } else {
            v0 = v1 = v2 = v3 = v4 = v5 = 0.f;
        }
        // input row r is the TOP tap of out row i, MID of i-1, BOTTOM of i-2
        if (i < RB) {
            acc[i][0] = fmaf(w00, v0, fmaf(w01, v1, fmaf(w02, v2, acc[i][0])));
            acc[i][1] = fmaf(w00, v1, fmaf(w01, v2, fmaf(w02, v3, acc[i][1])));
            acc[i][2] = fmaf(w00, v2, fmaf(w01, v3, fmaf(w02, v4, acc[i][2])));
            acc[i][3] = fmaf(w00, v3, fmaf(w01, v4, fmaf(w02, v5, acc[i][3])));
        }
        if (i >= 1 && i <= RB) {
            acc[i-1][0] = fmaf(w10, v0, fmaf(w11, v1, fmaf(w12, v2, acc[i-1][0])));
            acc[i-1][1] = fmaf(w10, v1, fmaf(w11, v2, fmaf(w12, v3, acc[i-1][1])));
            acc[i-1][2] = fmaf(w10, v2, fmaf(w11, v3, fmaf(w12, v4, acc[i-1][2])));
            acc[i-1][3] = fmaf(w10, v3, fmaf(w11, v4, fmaf(w12, v5, acc[i-1][3])));
        }
        if (i >= 2) {
            acc[i-2][0] = fmaf(w20, v0, fmaf(w21, v1, fmaf(w22, v2, acc[i-2][0])));
            acc[i-2][1] = fmaf(w20, v1, fmaf(w21, v2, fmaf(w22, v3, acc[i-2][1])));
            acc[i-2][2] = fmaf(w20, v2, fmaf(w21, v3, fmaf(w22, v4, acc[i-2][2])));
            acc[i-2][3] = fmaf(w20, v3, fmaf(w21, v4, fmaf(w22, v5, acc[i-2][3])));
        }
    }

    float* po = out + (size_t)plane * PLANE + y0 * W + x0;
    #pragma unroll
    for (int j = 0; j < RB; ++j) {
        floatx4 o = { acc[j][0], acc[j][1], acc[j][2], acc[j][3] };
        __builtin_nontemporal_store(o, (floatx4*)(po + j * W));
    }
}

extern "C" void kernel_launch(void* const* d_in, const int* in_sizes, int n_in,
                              void* d_out, int out_size, void* d_ws, size_t ws_size,
                              hipStream_t stream) {
    const float* x    = (const float*)d_in[0];
    const float* w1   = (const float*)d_in[1];
    const float* b1   = (const float*)d_in[2];
    const float* w2   = (const float*)d_in[3];
    const float* b2   = (const float*)d_in[4];
    const float* wb   = (const float*)d_in[5];
    const float* bias = (const float*)d_in[6];
    float* out = (float*)d_out;

    // workspace layout: pooled [2048] floats, cw [2048*9] floats
    float* pooled = (float*)d_ws;
    float* cw     = pooled + NPLANES;

    pool_kernel<<<NPLANES, 256, 0, stream>>>(x, pooled);
    selector_kernel<<<1, 512, 0, stream>>>(pooled, w1, b1, w2, b2, wb, cw);
    conv_kernel<<<NPLANES * 2, 576, 0, stream>>>(x, cw, bias, out);
}